// Round 11
// baseline (119.448 us; speedup 1.0000x reference)
//
#include <hip/hip_runtime.h>

// B=4, Sx=Sy=512, H=128, D=2H=256, fp32.
// e1 = exp2(2log2e * x@W1^T)  (stored PRE-SWIZZLED: [b][c][hq][s^hq] float4)
// e2 = exp2(2log2e * y@W2^T)  (linear)
// tanh(s1+s2) = 1 - 2/(e1*e2+1); score = sum_h vc[h]*tanh(.)
// constant sum_h vc[h] dropped (softmax shift-invariant); -2 folded into the
// cross-wave partial reduce. P = softmax_s(score); out = P @ x.
// Quad-rcp: v1/f1+..+v4/f4 = (n12*f34+n34*f12)/(f12*f34), one rcp per 4 h.
//
// R5-R7: allocator pins 512/1024-thr kernels at 32 VGPRs regardless of
// __launch_bounds__ and spills prefetch regs. Fix: global_load_lds DMA
// (zero staging VGPRs), e1 pre-swizzled in global so the DMA is a memcpy.
// R8: harness 256 MiB d_ws 0xAA fill = ~40 us of every timed iteration +
// ~25-35 us of tiny restore dispatches (immovable floor ~70 us).
// R9: pax rewrite -> ~6 us. R10: score t=4/block (neutral; kept).
// R11: proj fused to ONE kernel (no part round-trip); pax 512 blocks
// (d-half split, float2 lanes, acc=16 VGPR) -> 2 waves/SIMD.

#define NB 4
#define SEQ 512
#define HDIM 128
#define DDIM 256

static constexpr float TWO_LOG2E = 2.8853900817779268f; // 2*log2(e)
static constexpr float LOG2E     = 1.4426950408889634f;

__device__ __forceinline__ void gload_lds16(const void* g, void* l) {
    __builtin_amdgcn_global_load_lds(
        (const __attribute__((address_space(1))) void*)g,
        (__attribute__((address_space(3))) void*)l, 16, 0, 0);
}

// ---------------- Kernel A: projections + exp2, single kernel --------------
// 512 blocks x 256 thr. Block = 8 rows of 4096 virtual rows (x then y).
// Thread = (hq=tid&31, ks=tid>>5): 4h x 8r x 32k register block, full K=256.
// A-tile (8x256) in LDS broadcast; W from L2 (128 KB, hot). k-split over ks
// reduced through LDS; epilogue applies exp2 and writes e1 swizzled /
// e2 linear directly (combine kernel + 8 MB part round-trip eliminated).
__global__ __launch_bounds__(256) void proj_kernel(
    const float* __restrict__ x, const float* __restrict__ y,
    const float* __restrict__ W1, const float* __restrict__ W2,
    float* __restrict__ e1sw, float* __restrict__ e2)
{
    __shared__ float As[2048];      // [8 r][256 k]
    __shared__ float sPr[8192];     // [8 ks][8 r][128 h]
    const int tid = threadIdx.x;
    const int blk = blockIdx.x;           // [0,512)
    const int gr0 = blk * 8;              // global virtual row base [0,4096)

    const float* in; const float* W; int srow;
    if (gr0 < 2048) { in = x; W = W1; srow = gr0; }
    else            { in = y; W = W2; srow = gr0 - 2048; }

    {   // stage A: 8 rows x 256 k = 2048 floats (2 float4/thread)
        const int r = tid >> 5, kk = tid & 31;
        *(float4*)&As[r * 256 + kk * 8] =
            *(const float4*)&in[(srow + r) * 256 + kk * 8];
        *(float4*)&As[r * 256 + kk * 8 + 4] =
            *(const float4*)&in[(srow + r) * 256 + kk * 8 + 4];
    }
    __syncthreads();

    const int hq = tid & 31;
    const int ks = tid >> 5;       // k-range [32*ks, 32*ks+32)

    float4 acc4[8];
    #pragma unroll
    for (int r = 0; r < 8; ++r) acc4[r] = make_float4(0.f, 0.f, 0.f, 0.f);

    #pragma unroll
    for (int u = 0; u < 8; ++u) {
        const int kof = ks * 32 + u * 4;
        const float4 w0 = *(const float4*)&W[(4*hq + 0) * 256 + kof];
        const float4 w1 = *(const float4*)&W[(4*hq + 1) * 256 + kof];
        const float4 w2 = *(const float4*)&W[(4*hq + 2) * 256 + kof];
        const float4 w3 = *(const float4*)&W[(4*hq + 3) * 256 + kof];
        #pragma unroll
        for (int r = 0; r < 8; ++r) {
            const float4 a = *(const float4*)&As[r * 256 + kof];
            acc4[r].x = fmaf(a.w,w0.w, fmaf(a.z,w0.z, fmaf(a.y,w0.y, fmaf(a.x,w0.x, acc4[r].x))));
            acc4[r].y = fmaf(a.w,w1.w, fmaf(a.z,w1.z, fmaf(a.y,w1.y, fmaf(a.x,w1.x, acc4[r].y))));
            acc4[r].z = fmaf(a.w,w2.w, fmaf(a.z,w2.z, fmaf(a.y,w2.y, fmaf(a.x,w2.x, acc4[r].z))));
            acc4[r].w = fmaf(a.w,w3.w, fmaf(a.z,w3.z, fmaf(a.y,w3.y, fmaf(a.x,w3.x, acc4[r].w))));
        }
    }
    #pragma unroll
    for (int r = 0; r < 8; ++r)
        *(float4*)&sPr[ks * 1024 + r * 128 + hq * 4] = acc4[r];
    __syncthreads();
    {
        const int r = tid >> 5, h4 = tid & 31;   // h4 == output hq
        float4 s = make_float4(0.f, 0.f, 0.f, 0.f);
        #pragma unroll
        for (int k2 = 0; k2 < 8; ++k2) {
            const float4 p = *(const float4*)&sPr[k2 * 1024 + r * 128 + h4 * 4];
            s.x += p.x; s.y += p.y; s.z += p.z; s.w += p.w;
        }
        float4 o;
        o.x = __builtin_amdgcn_exp2f(s.x * TWO_LOG2E);
        o.y = __builtin_amdgcn_exp2f(s.y * TWO_LOG2E);
        o.z = __builtin_amdgcn_exp2f(s.z * TWO_LOG2E);
        o.w = __builtin_amdgcn_exp2f(s.w * TWO_LOG2E);
        const int gr = gr0 + r;
        if (gr < 2048) {
            const int b = gr >> 9, sx = gr & 511;
            const int c = sx >> 6, sl = sx & 63;
            ((float4*)e1sw)[((b * 8 + c) * 32 + h4) * 64 + (sl ^ h4)] = o;
        } else {
            ((float4*)e2)[(gr - 2048) * 32 + h4] = o;
        }
    }
}

// ---------------- Kernel B: scores + softmax -> P (unchanged R10) ----------
__global__ __launch_bounds__(1024) void score_kernel(
    const float* __restrict__ e1sw, const float* __restrict__ e2g,
    const float* __restrict__ vc,  float* __restrict__ P)
{
    __shared__ float4 sE1[2][2048];     // 2 x 32 KB
    __shared__ float  sScore[4 * 512];  // 8 KB
    __shared__ float  sPartC[2][1024];  // 2 x 4 KB, [w][lane]

    const int tid  = threadIdx.x;
    const int b    = blockIdx.x >> 7;
    const int t0   = (blockIdx.x & 127) * 4;
    const int w    = tid >> 6;
    const int lane = tid & 63;
    const int wu   = __builtin_amdgcn_readfirstlane(w);
    const int tU   = wu >> 2;          // t this wave serves (0..3)
    const int qU   = wu & 3;           // h-quarter (quads qU*8 .. qU*8+7)

    float4 vcs[8];
    float4 e2s[8];
    #pragma unroll
    for (int j = 0; j < 8; ++j) {
        vcs[j] = *(const float4*)&vc[(qU * 8 + j) * 4];
        e2s[j] = *(const float4*)&e2g[(b * SEQ + t0 + tU) * HDIM + (qU * 8 + j) * 4];
    }

    const float4* e1c = (const float4*)e1sw + b * 16384;  // 8 chunks x 2048

    #pragma unroll
    for (int j = 0; j < 2; ++j) {
        const int seg = wu * 128 + j * 64;
        gload_lds16(e1c + seg + lane, &sE1[0][seg]);
    }

    for (int c = 0; c < 8; ++c) {
        __syncthreads();   // drains DMA: buf[c&1] ready
        if (c < 7) {
            const float4* gch = e1c + (c + 1) * 2048;
            #pragma unroll
            for (int j = 0; j < 2; ++j) {
                const int seg = wu * 128 + j * 64;
                gload_lds16(gch + seg + lane, &sE1[(c + 1) & 1][seg]);
            }
        }
        if (c > 0 && tid < 256) {
            const int t = tid >> 6, s = tid & 63;
            const float* pc = sPartC[(c - 1) & 1];
            const float r = pc[(t*4+0)*64 + s] + pc[(t*4+1)*64 + s]
                          + pc[(t*4+2)*64 + s] + pc[(t*4+3)*64 + s];
            sScore[t * 512 + (c - 1) * 64 + s] = -2.f * r;
        }
        float acc = 0.f;
        const float4* buf = sE1[c & 1];
        #pragma unroll
        for (int j = 0; j < 8; ++j) {
            const int hq = qU * 8 + j;
            const float4 e1 = buf[hq * 64 + (lane ^ hq)];
            const float4 vv = vcs[j];
            const float4 e2 = e2s[j];
            const float f1 = fmaf(e1.x, e2.x, 1.f);
            const float f2 = fmaf(e1.y, e2.y, 1.f);
            const float f3 = fmaf(e1.z, e2.z, 1.f);
            const float f4 = fmaf(e1.w, e2.w, 1.f);
            const float f12 = f1 * f2, f34 = f3 * f4;
            const float n12 = fmaf(vv.x, f2, vv.y * f1);
            const float n34 = fmaf(vv.z, f4, vv.w * f3);
            const float num = fmaf(n12, f34, n34 * f12);
            acc = fmaf(num, __builtin_amdgcn_rcpf(f12 * f34), acc);
        }
        sPartC[c & 1][w * 64 + lane] = acc;
    }
    __syncthreads();
    if (tid < 256) {
        const int t = tid >> 6, s = tid & 63;
        const float* pc = sPartC[7 & 1];
        const float r = pc[(t*4+0)*64 + s] + pc[(t*4+1)*64 + s]
                      + pc[(t*4+2)*64 + s] + pc[(t*4+3)*64 + s];
        sScore[t * 512 + 7 * 64 + s] = -2.f * r;
    }
    __syncthreads();

    if (w < 4) {
        float v[8];
        float m = -1e30f;
        #pragma unroll
        for (int j = 0; j < 8; ++j) {
            v[j] = sScore[w * 512 + lane + j * 64];
            m = fmaxf(m, v[j]);
        }
        #pragma unroll
        for (int off = 32; off; off >>= 1) m = fmaxf(m, __shfl_xor(m, off));
        float sum = 0.f;
        #pragma unroll
        for (int j = 0; j < 8; ++j) {
            v[j] = __builtin_amdgcn_exp2f((v[j] - m) * LOG2E);
            sum += v[j];
        }
        #pragma unroll
        for (int off = 32; off; off >>= 1) sum += __shfl_xor(sum, off);
        const float inv = __builtin_amdgcn_rcpf(sum);
        float* Prow = &P[(b * SEQ + t0 + w) * SEQ];
        #pragma unroll
        for (int j = 0; j < 8; ++j)
            Prow[lane + j * 64] = v[j] * inv;
    }
}

// ---------------- Kernel C: out = P @ x ------------------------------------
// 512 blocks x 256 thr -> 2 waves/SIMD (R9 had 1; latency-exposed L2 loads).
// Block = (b, 8-t tile, 128-d half). Wave = s-quarter (128 s); lane = d-pair
// (float2). acc[8] float2 = 16 VGPRs (far from the 32-VGPR allocator pin).
// Per s: 1 global b64 (x, L2-hot) + 2 broadcast b128 (8 probs) -> 16 FMAs.
__global__ __launch_bounds__(256) void pax_kernel(
    const float* __restrict__ P, const float* __restrict__ x,
    float* __restrict__ out)
{
    __shared__ float sP[SEQ * 8];        // 16 KB: [s][t]
    __shared__ float sRed[4 * 8 * 128];  // 16 KB: [w][t][d-half]
    const int tid = threadIdx.x;
    const int b   = blockIdx.x >> 7;
    const int tt  = (blockIdx.x >> 1) & 63;   // 8-t tile
    const int dh  = blockIdx.x & 1;           // d-half
    const int t0  = tt * 8;
    const int w    = tid >> 6;
    const int lane = tid & 63;

    // stage P[b, t0..t0+7, :] transposed -> sP[s*8 + t]
    #pragma unroll
    for (int j = 0; j < 4; ++j) {
        const int i = tid + j * 256;          // [0,1024): t = i>>7, c4 = i&127
        const int t = i >> 7, c4 = i & 127;
        const float4 p = *(const float4*)&P[(b * SEQ + t0 + t) * SEQ + c4 * 4];
        sP[(c4 * 4 + 0) * 8 + t] = p.x;
        sP[(c4 * 4 + 1) * 8 + t] = p.y;
        sP[(c4 * 4 + 2) * 8 + t] = p.z;
        sP[(c4 * 4 + 3) * 8 + t] = p.w;
    }
    __syncthreads();

    const int dbase = dh * 128 + lane * 2;
    float2 acc[8];
    #pragma unroll
    for (int t = 0; t < 8; ++t) acc[t] = make_float2(0.f, 0.f);

    #pragma unroll 4
    for (int si = 0; si < 128; ++si) {
        const int s = w * 128 + si;
        const float2 xv  = *(const float2*)&x[(b * SEQ + s) * DDIM + dbase];
        const float4 p03 = *(const float4*)&sP[s * 8];
        const float4 p47 = *(const float4*)&sP[s * 8 + 4];
        acc[0].x = fmaf(p03.x, xv.x, acc[0].x); acc[0].y = fmaf(p03.x, xv.y, acc[0].y);
        acc[1].x = fmaf(p03.y, xv.x, acc[1].x); acc[1].y = fmaf(p03.y, xv.y, acc[1].y);
        acc[2].x = fmaf(p03.z, xv.x, acc[2].x); acc[2].y = fmaf(p03.z, xv.y, acc[2].y);
        acc[3].x = fmaf(p03.w, xv.x, acc[3].x); acc[3].y = fmaf(p03.w, xv.y, acc[3].y);
        acc[4].x = fmaf(p47.x, xv.x, acc[4].x); acc[4].y = fmaf(p47.x, xv.y, acc[4].y);
        acc[5].x = fmaf(p47.y, xv.x, acc[5].x); acc[5].y = fmaf(p47.y, xv.y, acc[5].y);
        acc[6].x = fmaf(p47.z, xv.x, acc[6].x); acc[6].y = fmaf(p47.z, xv.y, acc[6].y);
        acc[7].x = fmaf(p47.w, xv.x, acc[7].x); acc[7].y = fmaf(p47.w, xv.y, acc[7].y);
    }
    __syncthreads();
    float2* sRed2 = (float2*)sRed;     // [4 w][8 t][64 lane-pairs]
    #pragma unroll
    for (int t = 0; t < 8; ++t)
        sRed2[w * 512 + t * 64 + lane] = acc[t];
    __syncthreads();
    #pragma unroll
    for (int j = 0; j < 4; ++j) {
        const int i = tid + j * 256;   // [0,1024): t = i>>7, d = i&127
        const int t = i >> 7, d = i & 127;
        const float r = sRed[0*1024 + t*128 + d] + sRed[1*1024 + t*128 + d]
                      + sRed[2*1024 + t*128 + d] + sRed[3*1024 + t*128 + d];
        out[(b * SEQ + t0 + t) * DDIM + dh * 128 + d] = r;
    }
}

extern "C" void kernel_launch(void* const* d_in, const int* in_sizes, int n_in,
                              void* d_out, int out_size, void* d_ws, size_t ws_size,
                              hipStream_t stream) {
    const float* x   = (const float*)d_in[0];   // (4,512,256)
    const float* y   = (const float*)d_in[1];   // (4,512,256)
    const float* W1  = (const float*)d_in[2];   // (128,256)
    const float* W2  = (const float*)d_in[3];   // (128,256)
    const float* vc  = (const float*)d_in[4];   // (1,128)
    float* outp = (float*)d_out;                // (4,512,256)

    float* ws = (float*)d_ws;
    float* e1 = ws;                             // 1 MB (swizzled)
    float* e2 = ws + NB * SEQ * HDIM;           // 1 MB
    float* P  = ws + 2 * NB * SEQ * HDIM;       // 4 MB

    hipLaunchKernelGGL(proj_kernel,  dim3(512), dim3(256),  0, stream,
                       x, y, W1, W2, e1, e2);
    hipLaunchKernelGGL(score_kernel, dim3(512), dim3(1024), 0, stream,
                       e1, e2, vc, P);
    hipLaunchKernelGGL(pax_kernel,   dim3(512), dim3(256),  0, stream,
                       P, x, outp);
}